// Round 4
// baseline (123.422 us; speedup 1.0000x reference)
//
#include <hip/hip_runtime.h>
#include <math.h>

#define ROW_C 512
#define NBIN 2048
#define NPACK (NBIN / 2)   // two 16-bit counters per int -> 1024 ints = 4KB/wave

// TWO rows per wave, 8 elements/lane each, sharing one 4KB per-wave histogram
// sequentially with software-pipelined phases:
//   A:zero+atomics -> A:totals/scan/crossing (last LDS read of A)
//   B:zero+atomics            (issued early; in-order DS pipe makes this safe)
//   A:tail/zsum/epilogue/store (pure VALU/DPP -> hides B's DS latency)
//   B:totals/scan/crossing -> B:tail/zsum/epilogue/store
// Selection per row (verified in prior rounds):
//  1. value-uniform 2048-bin histogram over octave [8,16) (clamp +-3.90625,
//     +12.0 -> bin width 1/256; bits [22:12] monotone). Packed u16x2 LDS
//     counters, XOR-swizzled so int4 reads/writes are bank-conflict-free.
//  2. per-lane packed totals + DPP 64-lane inclusive scan (0 DS ops);
//     ballots locate each rank's owner lane; 16-lanes-per-rank crossing scan
//     (one word/lane, 4-step DPP row scan, ballot) -> bsel, R-within-bin,
//     all-in predicate; per-rank results to SGPRs via v_readlane.
//  3. nested-set float thresholds t1>=t2>=t3>=t4 (all-in -> exact bin lower
//     edge, bin<=24 -> -inf; partial -> exact tail wave-max via DPP+readlane);
//     membership = x>=t_r; epilogue = 4-deep cndmask chain into wz prefix sums.
//  4. rare exact-duplicate index-tiebreak -> wave-uniform fallback (matches
//     jax.lax.top_k lowest-index rule).
// bins/eo recomputed at use sites (not kept live) to hold VGPR down.
// Softmax shift term omitted (shift-invariant). No __syncthreads (wave-private
// LDS, in-order DS pipe). Assumes finite inputs.

static __device__ __forceinline__ unsigned scan64_add(unsigned v) {
    int x = (int)v;
    x += __builtin_amdgcn_update_dpp(0, x, 0x111, 0xF, 0xF, false); // row_shr:1
    x += __builtin_amdgcn_update_dpp(0, x, 0x112, 0xF, 0xF, false); // row_shr:2
    x += __builtin_amdgcn_update_dpp(0, x, 0x114, 0xF, 0xE, false); // row_shr:4
    x += __builtin_amdgcn_update_dpp(0, x, 0x118, 0xF, 0xC, false); // row_shr:8
    x += __builtin_amdgcn_update_dpp(0, x, 0x142, 0xA, 0xF, false); // row_bcast:15
    x += __builtin_amdgcn_update_dpp(0, x, 0x143, 0xC, 0xF, false); // row_bcast:31
    return (unsigned)x;
}

static __device__ __forceinline__ unsigned scan16_add(unsigned v) {
    int x = (int)v;
    x += __builtin_amdgcn_update_dpp(0, x, 0x111, 0xF, 0xF, false);
    x += __builtin_amdgcn_update_dpp(0, x, 0x112, 0xF, 0xF, false);
    x += __builtin_amdgcn_update_dpp(0, x, 0x114, 0xF, 0xE, false);
    x += __builtin_amdgcn_update_dpp(0, x, 0x118, 0xF, 0xC, false);
    return (unsigned)x;
}

static __device__ __forceinline__ float wave_fadd_red(float v) {
    float t;
    t = __int_as_float(__builtin_amdgcn_update_dpp(0, __float_as_int(v), 0x111, 0xF, 0xF, false)); v += t;
    t = __int_as_float(__builtin_amdgcn_update_dpp(0, __float_as_int(v), 0x112, 0xF, 0xF, false)); v += t;
    t = __int_as_float(__builtin_amdgcn_update_dpp(0, __float_as_int(v), 0x114, 0xF, 0xE, false)); v += t;
    t = __int_as_float(__builtin_amdgcn_update_dpp(0, __float_as_int(v), 0x118, 0xF, 0xC, false)); v += t;
    t = __int_as_float(__builtin_amdgcn_update_dpp(0, __float_as_int(v), 0x142, 0xA, 0xF, false)); v += t;
    t = __int_as_float(__builtin_amdgcn_update_dpp(0, __float_as_int(v), 0x143, 0xC, 0xF, false)); v += t;
    return __int_as_float(__builtin_amdgcn_readlane(__float_as_int(v), 63));
}

static __device__ __forceinline__ float wave_fmax_red(float v) {
    const int NI = (int)0xFF800000;
    float t;
    t = __int_as_float(__builtin_amdgcn_update_dpp(NI, __float_as_int(v), 0x111, 0xF, 0xF, false)); v = fmaxf(v, t);
    t = __int_as_float(__builtin_amdgcn_update_dpp(NI, __float_as_int(v), 0x112, 0xF, 0xF, false)); v = fmaxf(v, t);
    t = __int_as_float(__builtin_amdgcn_update_dpp(NI, __float_as_int(v), 0x114, 0xF, 0xE, false)); v = fmaxf(v, t);
    t = __int_as_float(__builtin_amdgcn_update_dpp(NI, __float_as_int(v), 0x118, 0xF, 0xC, false)); v = fmaxf(v, t);
    t = __int_as_float(__builtin_amdgcn_update_dpp(NI, __float_as_int(v), 0x142, 0xA, 0xF, false)); v = fmaxf(v, t);
    t = __int_as_float(__builtin_amdgcn_update_dpp(NI, __float_as_int(v), 0x143, 0xC, 0xF, false)); v = fmaxf(v, t);
    return __int_as_float(__builtin_amdgcn_readlane(__float_as_int(v), 63));
}

__global__ __launch_bounds__(256) void topk_ms_kernel(
    const float* __restrict__ attn,
    const float* __restrict__ w1p, const float* __restrict__ w2p,
    const float* __restrict__ w3p, const float* __restrict__ w4p,
    float* __restrict__ out)
{
    __shared__ __align__(16) unsigned hist_all[4][NPACK];

    const int lane = threadIdx.x & 63;
    const int wv   = threadIdx.x >> 6;
    unsigned* h = hist_all[wv];
    int4* hv = (int4*)h;

    const long long gid   = (long long)blockIdx.x * 4 + wv;   // wave = row pair
    const long long baseA = gid * (2 * ROW_C) + lane * 8;
    const long long baseB = baseA + ROW_C;

    float xA[8], xB[8];
    {
        const float4 A0 = *reinterpret_cast<const float4*>(attn + baseA);
        const float4 A1 = *reinterpret_cast<const float4*>(attn + baseA + 4);
        const float4 B0 = *reinterpret_cast<const float4*>(attn + baseB);
        const float4 B1 = *reinterpret_cast<const float4*>(attn + baseB + 4);
        xA[0]=A0.x; xA[1]=A0.y; xA[2]=A0.z; xA[3]=A0.w;
        xA[4]=A1.x; xA[5]=A1.y; xA[6]=A1.z; xA[7]=A1.w;
        xB[0]=B0.x; xB[1]=B0.y; xB[2]=B0.z; xB[3]=B0.w;
        xB[4]=B1.x; xB[5]=B1.y; xB[6]=B1.z; xB[7]=B1.w;
    }

    const float NINF = -__builtin_inff();

    auto BINF = [](float v) -> int {
        const float y = __builtin_amdgcn_fmed3f(v, -3.90625f, 3.90625f) + 12.0f;
        return (int)((__float_as_uint(y) >> 12) & 0x7FFu);   // monotone, width 1/256
    };

    auto ZERO = [&]() {
        const int4 z = make_int4(0, 0, 0, 0);
        hv[lane] = z; hv[lane + 64] = z; hv[lane + 128] = z; hv[lane + 192] = z;
    };

    auto HIST = [&](const float* x) {
        #pragma unroll
        for (int s = 0; s < 8; ++s) {
            const int b  = BINF(x[s]);
            const int j  = b >> 1;
            const int ph = j ^ ((j >> 3) & 0x1C);   // XOR swizzle bits[7:5]->[4:2]
            atomicAdd(&h[ph], (b & 1) ? 0x10000u : 1u);
        }
    };

    // selection front-end: histogram -> per-rank {threshold, bin, R, all-in}
    auto FRONT = [&](float* tthr, int* b_, int* R_, int* al_) {
        unsigned ps = 0;
        #pragma unroll
        for (int k = 0; k < 4; ++k) {
            const int b  = 4 * lane + k;
            const int pb = b ^ ((b >> 3) & 7);
            const int4 v = hv[pb];
            ps += (unsigned)v.x + (unsigned)v.y + (unsigned)v.z + (unsigned)v.w;
        }
        const unsigned tot  = (ps & 0xFFFFu) + (ps >> 16);
        const unsigned incl = scan64_add(tot);
        const unsigned excl = incl - tot;

        const unsigned long long Ba = __ballot(incl >= 257u);
        const unsigned long long Bb = __ballot(incl >= 172u);
        const unsigned long long Bc = __ballot(incl >= 129u);
        const unsigned long long Bd = __ballot(incl >= 104u);
        const int l0 = __ffsll(Ba) - 1, l1 = __ffsll(Bb) - 1,
                  l2 = __ffsll(Bc) - 1, l3 = __ffsll(Bd) - 1;

        const int r = lane >> 4;
        const int lsel = (r == 0) ? l0 : (r == 1) ? l1 : (r == 2) ? l2 : l3;
        const int Tr   = (r == 0) ? 257 : (r == 1) ? 172 : (r == 2) ? 129 : 104;
        const int Kr   = (r == 0) ? 256 : (r == 1) ? 341 : (r == 2) ? 384 : 409;
        const unsigned exl = __shfl(excl, lsel, 64);

        const int jw = (lsel << 4) + (lane & 15);
        const int pw = jw ^ ((jw >> 3) & 0x1C);
        const unsigned w0 = h[pw];
        const unsigned q  = w0 + (w0 << 16);       // packed (even, even+odd)
        const unsigned wt = q >> 16;
        const unsigned sc = scan16_add(wt);
        const unsigned ebase = exl + (sc - wt);
        const int      phi   = (int)(ebase + wt);
        const unsigned long long CB = __ballot(phi >= Tr);
        const int js = __ffs((unsigned)(CB >> (r << 4))) - 1;
        const unsigned q_w  = __shfl(q, (r << 4) + js, 64);
        const unsigned eb_w = __shfl(ebase, (r << 4) + js, 64);

        const int  plo  = (int)(eb_w + (q_w & 0xFFFFu));
        const int  phw  = (int)(eb_w + (q_w >> 16));
        const bool ev   = (plo >= Tr);
        const int  bsel = (((lsel << 4) + js) << 1) + (ev ? 0 : 1);
        const int  locp = ev ? plo : phw;
        const int  prvp = ev ? (int)eb_w : plo;
        const int  Rr   = Kr - 512 + locp;
        const int  alin = (prvp == Tr - 1) ? 1 : 0;
        const unsigned pk = ((unsigned)bsel << 11) | ((unsigned)alin << 10) | (unsigned)Rr;

        const unsigned v0 = (unsigned)__builtin_amdgcn_readlane((int)pk, 0);
        const unsigned v1 = (unsigned)__builtin_amdgcn_readlane((int)pk, 16);
        const unsigned v2 = (unsigned)__builtin_amdgcn_readlane((int)pk, 32);
        const unsigned v3 = (unsigned)__builtin_amdgcn_readlane((int)pk, 48);
        const unsigned vv[4] = {v0, v1, v2, v3};
        #pragma unroll
        for (int rr = 0; rr < 4; ++rr) {
            b_[rr]  = (int)(vv[rr] >> 11);
            al_[rr] = (int)((vv[rr] >> 10) & 1u);
            R_[rr]  = (int)(vv[rr] & 0x3FFu);
            float t = __uint_as_float((unsigned)(b_[rr] + 0x41000) << 12) - 12.0f;
            tthr[rr] = (b_[rr] <= 24) ? NINF : t;  // low clamp bin: admit all
        }
    };

    // back-end: exact tail + softmax + weighted epilogue + store (LDS-free)
    auto BACK = [&](const float* x, float* tthr, const int* b_, const int* R_,
                    const int* al_, long long obase) {
        int needv[4] = {0,0,0,0}, cntv[4] = {0,0,0,0};
        bool anytb = false;
        const bool needbins = !(al_[0] && al_[1] && al_[2] && al_[3]);
        int bn[8];
        if (needbins) {
            #pragma unroll
            for (int s = 0; s < 8; ++s) bn[s] = BINF(x[s]);
        }
        #pragma unroll
        for (int rr = 0; rr < 4; ++rr) {
            if (!al_[rr]) {                        // wave-uniform (SGPR) branch
                float cm[8];
                #pragma unroll
                for (int s = 0; s < 8; ++s)
                    cm[s] = (bn[s] == b_[rr]) ? x[s] : NINF;
                int R = R_[rr];
                float t; int c;
                while (true) {
                    float mk = cm[0];
                    #pragma unroll
                    for (int s = 1; s < 8; ++s) mk = fmaxf(mk, cm[s]);
                    t = wave_fmax_red(mk);
                    c = 0;
                    #pragma unroll
                    for (int s = 0; s < 8; ++s)
                        c += (int)__popcll(__ballot(cm[s] == t));
                    if (c >= R) break;
                    R -= c;
                    #pragma unroll
                    for (int s = 0; s < 8; ++s)
                        cm[s] = (cm[s] == t) ? NINF : cm[s];
                }
                tthr[rr] = t; needv[rr] = R; cntv[rr] = c;
                anytb = anytb || (c != R);
            }
        }

        float eo[8];
        #pragma unroll
        for (int s = 0; s < 8; ++s) eo[s] = __expf(x[s]);

        float res[8];
        if (!anytb) {
            // fast path: 4 nested float thresholds t1>=t2>=t3>=t4
            const float t1 = tthr[0], t2 = tthr[1], t3 = tthr[2], t4 = tthr[3];
            float z0 = 0.f, z1 = 0.f, z2 = 0.f, z3 = 0.f;
            #pragma unroll
            for (int s = 0; s < 8; ++s) {
                z0 += (x[s] >= t1) ? eo[s] : 0.f;
                z1 += (x[s] >= t2) ? eo[s] : 0.f;
                z2 += (x[s] >= t3) ? eo[s] : 0.f;
                z3 += (x[s] >= t4) ? eo[s] : 0.f;
            }
            const float Z0 = wave_fadd_red(z0);
            const float Z1 = wave_fadd_red(z1);
            const float Z2 = wave_fadd_red(z2);
            const float Z3 = wave_fadd_red(z3);
            const float wz0 = w1p[0] * __builtin_amdgcn_rcpf(Z0);
            const float wz1 = w2p[0] * __builtin_amdgcn_rcpf(Z1);
            const float wz2 = w3p[0] * __builtin_amdgcn_rcpf(Z2);
            const float wz3 = w4p[0] * __builtin_amdgcn_rcpf(Z3);
            const float u4 = wz3, u3 = u4 + wz2, u2 = u3 + wz1, u1 = u2 + wz0;
            #pragma unroll
            for (int s = 0; s < 8; ++s) {
                float c = (x[s] >= t1) ? u1 : u2;
                c = (x[s] >= t2) ? c : u3;
                c = (x[s] >= t3) ? c : u4;
                c = (x[s] >= t4) ? c : 0.f;
                res[s] = eo[s] * c;
            }
        } else {
            // slow path (exact-duplicate tiebreak): general fl bitmask
            int fl[8] = {0, 0, 0, 0, 0, 0, 0, 0};
            #pragma unroll
            for (int rr = 0; rr < 4; ++rr) {
                const float t = tthr[rr];
                if (al_[rr] || needv[rr] == cntv[rr]) {
                    #pragma unroll
                    for (int s = 0; s < 8; ++s)
                        fl[s] |= ((int)(x[s] >= t)) << rr;
                } else {                            // admit lowest original idx
                    const unsigned long long ltm = (1ull << lane) - 1ull;
                    int basec = 0;
                    #pragma unroll
                    for (int s = 0; s < 8; ++s)
                        basec += (int)__popcll(__ballot(x[s] == t) & ltm);
                    int own = 0;
                    #pragma unroll
                    for (int s = 0; s < 8; ++s) {
                        const bool eq = (x[s] == t);
                        if (x[s] > t || (eq && (basec + own) < needv[rr]))
                            fl[s] |= (1 << rr);
                        own += eq ? 1 : 0;
                    }
                }
            }
            float z0 = 0.f, z1 = 0.f, z2 = 0.f, z3 = 0.f;
            #pragma unroll
            for (int s = 0; s < 8; ++s) {
                z0 += (fl[s] & 1) ? eo[s] : 0.f;
                z1 += (fl[s] & 2) ? eo[s] : 0.f;
                z2 += (fl[s] & 4) ? eo[s] : 0.f;
                z3 += (fl[s] & 8) ? eo[s] : 0.f;
            }
            const float Z0 = wave_fadd_red(z0);
            const float Z1 = wave_fadd_red(z1);
            const float Z2 = wave_fadd_red(z2);
            const float Z3 = wave_fadd_red(z3);
            const float wz0 = w1p[0] * __builtin_amdgcn_rcpf(Z0);
            const float wz1 = w2p[0] * __builtin_amdgcn_rcpf(Z1);
            const float wz2 = w3p[0] * __builtin_amdgcn_rcpf(Z2);
            const float wz3 = w4p[0] * __builtin_amdgcn_rcpf(Z3);
            #pragma unroll
            for (int s = 0; s < 8; ++s) {
                float c = 0.f;
                c += (fl[s] & 1) ? wz0 : 0.f;
                c += (fl[s] & 2) ? wz1 : 0.f;
                c += (fl[s] & 4) ? wz2 : 0.f;
                c += (fl[s] & 8) ? wz3 : 0.f;
                res[s] = eo[s] * c;
            }
        }

        *reinterpret_cast<float4*>(out + obase)     = make_float4(res[0], res[1], res[2], res[3]);
        *reinterpret_cast<float4*>(out + obase + 4) = make_float4(res[4], res[5], res[6], res[7]);
    };

    // ---- pipelined schedule ----
    ZERO();                                   // histogram for row A
    HIST(xA);
    float tthrA[4]; int bA[4], RA[4], alA[4];
    FRONT(tthrA, bA, RA, alA);                // last LDS read for row A

    ZERO();                                   // re-zero for row B (in-order DS
    HIST(xB);                                 // pipe: safe after A's reads)

    BACK(xA, tthrA, bA, RA, alA, baseA);      // pure VALU/DPP + store: hides
                                              // row B's atomic latency
    float tthrB[4]; int bB[4], RB[4], alB[4];
    FRONT(tthrB, bB, RB, alB);
    BACK(xB, tthrB, bB, RB, alB, baseB);
}

extern "C" void kernel_launch(void* const* d_in, const int* in_sizes, int n_in,
                              void* d_out, int out_size, void* d_ws, size_t ws_size,
                              hipStream_t stream) {
    const float* attn = (const float*)d_in[0];
    const float* w1   = (const float*)d_in[1];
    const float* w2   = (const float*)d_in[2];
    const float* w3   = (const float*)d_in[3];
    const float* w4   = (const float*)d_in[4];
    float* out = (float*)d_out;

    int rows  = in_sizes[0] / ROW_C;          // 8*8*512 = 32768
    int waves = rows / 2;                     // 2 rows per wave
    int blocks = (waves + 3) / 4;             // 4 waves per 256-thread block
    topk_ms_kernel<<<blocks, 256, 0, stream>>>(attn, w1, w2, w3, w4, out);
}